// Round 1
// baseline (1168.964 us; speedup 1.0000x reference)
//
#include <hip/hip_runtime.h>

#define BATCH 256
#define TSTEPS 2048
#define INSZ 64
#define HID 128
#define OUTSZ 64

// One workgroup per batch element; 256 threads = (j=tid>>1 output, s=tid&1 k-half).
// Wh/Wx row-halves in registers; h double-buffered in LDS; x staged in 16-step chunks.
__launch_bounds__(256, 1)
__global__ void rnn_fused_kernel(const float* __restrict__ x,
                                 const float* __restrict__ Wx_w,
                                 const float* __restrict__ Wx_b,
                                 const float* __restrict__ Wh_w,
                                 const float* __restrict__ Wh_b,
                                 const float* __restrict__ fc_w,
                                 const float* __restrict__ fc_b,
                                 float* __restrict__ out) {
  const int b = blockIdx.x;
  const int tid = threadIdx.x;
  const int s = tid & 1;   // k-half: 0 -> k in [0,64), 1 -> k in [64,128)
  const int j = tid >> 1;  // hidden output index 0..127

  __shared__ __align__(16) float hbuf[2][HID];
  __shared__ __align__(16) float xbuf[2][16 * INSZ];  // 16 timesteps per chunk

  // ---- preload weights into registers ----
  float wh[64];
  const float* whp = Wh_w + j * HID + s * 64;
#pragma unroll
  for (int i = 0; i < 64; i += 4) *(float4*)&wh[i] = *(const float4*)&whp[i];

  float wx[32];
  const float* wxp = Wx_w + j * INSZ + s * 32;
#pragma unroll
  for (int i = 0; i < 32; i += 4) *(float4*)&wx[i] = *(const float4*)&wxp[i];

  const float bc = Wx_b[j] + Wh_b[j];  // combined bias

  const float* xg = x + (size_t)b * TSTEPS * INSZ;

  // ---- init: h0 = 0, stage chunk 0 (timesteps 0..15 = 1024 floats) ----
  if (s == 0) hbuf[0][j] = 0.f;
  {
    float4 v = ((const float4*)xg)[tid];  // 256 threads * 16B = 4KB coalesced
    ((float4*)&xbuf[0][0])[tid] = v;
  }
  __syncthreads();

  // ---- recurrence over T steps ----
  for (int t = 0; t < TSTEPS; ++t) {
    const int p = t & 1;

    // stage next 16-step chunk of x into the other buffer
    if ((t & 15) == 0 && (t + 16) < TSTEPS) {
      float4 v = ((const float4*)(xg + (size_t)(t + 16) * INSZ))[tid];
      ((float4*)&xbuf[((t >> 4) + 1) & 1][0])[tid] = v;
    }

    const float* hs = &hbuf[p][s * 64];
    const float* xs = &xbuf[(t >> 4) & 1][(t & 15) * INSZ + s * 32];

    float a0 = 0.f, a1 = 0.f, a2 = 0.f, a3 = 0.f;
#pragma unroll
    for (int i = 0; i < 64; i += 4) {
      float4 hv = *(const float4*)&hs[i];
      a0 = fmaf(wh[i + 0], hv.x, a0);
      a1 = fmaf(wh[i + 1], hv.y, a1);
      a2 = fmaf(wh[i + 2], hv.z, a2);
      a3 = fmaf(wh[i + 3], hv.w, a3);
    }
#pragma unroll
    for (int i = 0; i < 32; i += 4) {
      float4 xv = *(const float4*)&xs[i];
      a0 = fmaf(wx[i + 0], xv.x, a0);
      a1 = fmaf(wx[i + 1], xv.y, a1);
      a2 = fmaf(wx[i + 2], xv.z, a2);
      a3 = fmaf(wx[i + 3], xv.w, a3);
    }
    float acc = (a0 + a1) + (a2 + a3);
    acc += __shfl_xor(acc, 1, 64);  // combine the two k-halves (lanes 2j, 2j+1)

    // h_new = tanh(acc + bias) = 1 - 2/(exp2(z*2*log2e)+1)
    float z = acc + bc;
    float e = __builtin_amdgcn_exp2f(z * 2.885390081777927f);  // 2*log2(e)
    float hn = 1.f - 2.f * __builtin_amdgcn_rcpf(e + 1.f);

    if (s == 0) hbuf[p ^ 1][j] = hn;
    __syncthreads();
  }

  // ---- epilogue: logits = h_T @ fc_w^T + fc_b, softmax over 64, one wave ----
  // T even -> final h is in hbuf[0]
  if (tid < 64) {
    const float* fr = fc_w + tid * HID;
    float a = fc_b[tid];
#pragma unroll
    for (int k = 0; k < HID; k += 4) {
      float4 w4 = *(const float4*)&fr[k];
      a = fmaf(w4.x, hbuf[0][k + 0], a);
      a = fmaf(w4.y, hbuf[0][k + 1], a);
      a = fmaf(w4.z, hbuf[0][k + 2], a);
      a = fmaf(w4.w, hbuf[0][k + 3], a);
    }
    float m = a;
#pragma unroll
    for (int off = 32; off >= 1; off >>= 1) m = fmaxf(m, __shfl_xor(m, off, 64));
    float e = __builtin_amdgcn_exp2f((a - m) * 1.4426950408889634f);
    float ssum = e;
#pragma unroll
    for (int off = 32; off >= 1; off >>= 1) ssum += __shfl_xor(ssum, off, 64);
    out[b * OUTSZ + tid] = e / ssum;
  }
}

extern "C" void kernel_launch(void* const* d_in, const int* in_sizes, int n_in,
                              void* d_out, int out_size, void* d_ws, size_t ws_size,
                              hipStream_t stream) {
  const float* x    = (const float*)d_in[0];
  const float* Wx_w = (const float*)d_in[1];
  const float* Wx_b = (const float*)d_in[2];
  const float* Wh_w = (const float*)d_in[3];
  const float* Wh_b = (const float*)d_in[4];
  const float* fc_w = (const float*)d_in[5];
  const float* fc_b = (const float*)d_in[6];
  float* out = (float*)d_out;

  rnn_fused_kernel<<<BATCH, 256, 0, stream>>>(x, Wx_w, Wx_b, Wh_w, Wh_b, fc_w, fc_b, out);
}